// Round 2
// baseline (387.766 us; speedup 1.0000x reference)
//
#include <hip/hip_runtime.h>
#include <stdint.h>

// QuantConv1d: out[m][n] = (sum_k x[m][k]*w[k][n]) * scale[n] + bias[n]
// m=256, k=4096, n=16384. w arrives as int32 (harness-widened int8): 256 MiB stream.
// R1: xb stored A-fragment-major so A-loads are coalesced 1KiB wave reads.
// R2: single-barrier pipeline, LDS double-buffer, issue order A(it)->W(it+1)->
//     convert(W(it)) so vmcnt waits never drain the in-flight W queue.
// R3: BN 64->32, grid 256->512 => 2 blocks/CU (4 waves/SIMD). Discriminates
//     "gemm at W-stream floor" vs "1-block/CU barrier lockstep": a co-resident
//     block absorbs per-iter barrier stalls. W still fetched exactly once
//     (disjoint 32-col stripes); per-CU W/A traffic unchanged; old wn A-read
//     duplication eliminated (8 waves = 8 distinct m32-tiles x 1 shared n32).

typedef short bf16x8 __attribute__((ext_vector_type(8)));   // 8 bf16 = 16 B (MFMA A/B frag)
typedef float f32x16 __attribute__((ext_vector_type(16)));  // MFMA 32x32 accumulator
typedef int   i32x4  __attribute__((ext_vector_type(4)));
typedef int   i32x2  __attribute__((ext_vector_type(2)));
typedef unsigned short u16x4 __attribute__((ext_vector_type(4)));

#define K_DIM 4096
#define N_DIM 16384
#define BK 128
#define BN 32
#define NIT (K_DIM / BK)   // 32 K-iterations
#define KSTEPS 256         // K_DIM/16 total MFMA k-steps

__device__ __forceinline__ unsigned fbits(float f) {
  union { float f; unsigned u; } c; c.f = f; return c.u;
}
__device__ __forceinline__ unsigned short bf16rne(float f) {
  unsigned u = fbits(f);
  return (unsigned short)((u + 0x7FFFu + ((u >> 16) & 1u)) >> 16);
}

// ---------------- kernel 1: x fp32 -> bf16, A-fragment-major ----------------
// chunk c = (mt*256 + ks)*64 + lane holds A[m = mt*32 + (lane&31)]
//                                        [k = ks*16 + (lane>>5)*8 .. +8]  (16 B)
// => a wave's A-frag read for (mt, ks) is 64 contiguous 16 B chunks = 1 KiB.
__global__ __launch_bounds__(256) void cvt_x_frag(const float* __restrict__ x,
                                                  unsigned short* __restrict__ xb) {
  int c    = blockIdx.x * 256 + threadIdx.x;   // 131072 chunks
  int lane = c & 63;
  int ks   = (c >> 6) & 255;
  int mt   = c >> 14;
  int row  = mt * 32 + (lane & 31);
  int k0   = ks * 16 + (lane >> 5) * 8;
  const float4* p = (const float4*)(x + row * K_DIM + k0);
  float4 v0 = p[0], v1 = p[1];
  u16x4 o0, o1;
  o0.x = bf16rne(v0.x); o0.y = bf16rne(v0.y); o0.z = bf16rne(v0.z); o0.w = bf16rne(v0.w);
  o1.x = bf16rne(v1.x); o1.y = bf16rne(v1.y); o1.z = bf16rne(v1.z); o1.w = bf16rne(v1.w);
  u16x4* dst = (u16x4*)(xb + (size_t)c * 8);
  dst[0] = o0;
  dst[1] = o1;
}

// ---------------- kernel 2: GEMM ----------------
// block: 512 thr = 8 waves, wave w owns m-tile mt=w (rows w*32..w*32+31) x the
// block's single n32-tile. grid: 512 blocks; block bx owns output columns
// [bx*32, bx*32+32) for ALL 256 rows => every W element fetched from HBM once.
__global__ __launch_bounds__(512, 4) void gemm_qconv(
    const unsigned short* __restrict__ xb,   // A-fragment-major bf16 (see cvt)
    const int* __restrict__ w,               // [4096][16384] int32
    const float* __restrict__ scale,
    const float* __restrict__ bias,
    float* __restrict__ out) {
  // B fragment store: kstep s = 0..7; slot sigma = khalf*32 + (n&31); reader lane
  // reads slot==lane => contiguous ds_read_b128. 8 KiB per buffer, x2 dbuf.
  __shared__ i32x4 Blds[2][8 * 64];

  const int tid  = threadIdx.x;
  const int lane = tid & 63;
  const int wave = tid >> 6;                 // 0..7 : m32-tile
  const int l31  = lane & 31;
  const int half = lane >> 5;
  const int n0   = blockIdx.x * BN;

  // ---- W staging: thread t covers 4 k-rows x 2 n-columns per iter (32 B) ----
  const int n2 = tid & 15;                   // column pair (2*n2, 2*n2+1)
  const int r8 = tid >> 4;                   // 0..31 : k-rows [r8*4, r8*4+4)
  const int sW = r8 >> 2;                    // kstep this thread feeds
  const int hW = (r8 >> 1) & 1;              // k-half within kstep
  const int q8 = r8 & 1;                     // which 4-of-8 k-slot half (8 B offs)
  const int nnA = n2 * 2, nnB = n2 * 2 + 1;
  // i32x2 index into the buffer: slot*2 + q8
  const int slotA = (sW * 64 + hW * 32 + nnA) * 2 + q8;
  const int slotB = (sW * 64 + hW * 32 + nnB) * 2 + q8;

  const int* wbase = w + (r8 * 4) * N_DIM + n0 + n2 * 2;

  // prologue: prefetch W regs for iter 0 (8 ints = 4 x dwordx2, 128B row segs)
  i32x2 La[4], Lb[4];
#pragma unroll
  for (int i = 0; i < 4; ++i) La[i] = *(const i32x2*)(wbase + i * N_DIM);

  f32x16 acc = {};

  // A-fragment base: wave owns m-tile mt = wave
  const bf16x8* afrag = (const bf16x8*)(xb + (size_t)(wave * KSTEPS) * 64 * 8);

  // Per-iteration body. Vmcnt queue at MFMA time: [A(IT) x8, W(IT+1) x4]
  //  - convert waits W(IT)  -> vmcnt(12): A + next W stay in flight
  //  - MFMA waits A(IT)     -> vmcnt(4):  next W stays in flight
  // Raw s_barrier (no vmcnt drain); lgkmcnt(0) makes ds_writes visible.
  // Double buffer => read(buf)@IT vs next write(buf)@IT+2 separated by the
  // IT+1 barrier + its lgkmcnt(0) => race-free with ONE barrier/iter.
#define ITER_BODY(IT, LCUR, LNEXT, BUFIDX)                                     \
  {                                                                            \
    bf16x8 A[8];                                                               \
    _Pragma("unroll")                                                          \
    for (int s = 0; s < 8; ++s) {                                              \
      A[s] = afrag[((IT) * 8 + s) * 64 + lane];                                \
    }                                                                          \
    __builtin_amdgcn_sched_barrier(0); /* pin: A issues before next W */       \
    {                                                                          \
      const int itn = ((IT) + 1 < NIT) ? (IT) + 1 : NIT - 1; /* dead@31=DCE */ \
      const int* wp = wbase + (size_t)itn * (BK * N_DIM);                      \
      _Pragma("unroll")                                                        \
      for (int i = 0; i < 4; ++i) LNEXT[i] = *(const i32x2*)(wp + i * N_DIM);  \
    }                                                                          \
    __builtin_amdgcn_sched_barrier(0); /* pin: W issues before convert wait */ \
    i32x2 chA, chB;                                                            \
    {                                                                          \
      float a0 = (float)LCUR[0].x, a1 = (float)LCUR[1].x;                      \
      float a2 = (float)LCUR[2].x, a3 = (float)LCUR[3].x;                      \
      float b0 = (float)LCUR[0].y, b1 = (float)LCUR[1].y;                      \
      float b2 = (float)LCUR[2].y, b3 = (float)LCUR[3].y;                      \
      chA.x = (int)__builtin_amdgcn_perm(fbits(a1), fbits(a0), 0x07060302u);   \
      chA.y = (int)__builtin_amdgcn_perm(fbits(a3), fbits(a2), 0x07060302u);   \
      chB.x = (int)__builtin_amdgcn_perm(fbits(b1), fbits(b0), 0x07060302u);   \
      chB.y = (int)__builtin_amdgcn_perm(fbits(b3), fbits(b2), 0x07060302u);   \
    }                                                                          \
    {                                                                          \
      i32x2* bb = (i32x2*)&Blds[BUFIDX][0];                                    \
      bb[slotA] = chA;                                                         \
      bb[slotB] = chB;                                                         \
    }                                                                          \
    asm volatile("s_waitcnt lgkmcnt(0)" ::: "memory");                         \
    __builtin_amdgcn_s_barrier();                                              \
    __builtin_amdgcn_sched_barrier(0); /* no LDS reads above the barrier */    \
    _Pragma("unroll")                                                          \
    for (int s = 0; s < 8; ++s) {                                              \
      bf16x8 b = *(const bf16x8*)&Blds[BUFIDX][s * 64 + lane];                 \
      acc = __builtin_amdgcn_mfma_f32_32x32x16_bf16(A[s], b, acc, 0, 0, 0);    \
    }                                                                          \
  }

#pragma unroll 1
  for (int it = 0; it < NIT; it += 2) {
    ITER_BODY(it,     La, Lb, 0)
    ITER_BODY(it + 1, Lb, La, 1)
  }
#undef ITER_BODY

  // epilogue: C/D map col=lane&31, row=(reg&3)+8*(reg>>2)+4*half
  const int n = n0 + l31;
  const float sc = scale[n];
  const float bs = bias[n];
#pragma unroll
  for (int g = 0; g < 16; ++g) {
    const int m = wave * 32 + (g & 3) + 8 * (g >> 2) + 4 * half;
    out[m * N_DIM + n] = acc[g] * sc + bs;
  }
}

extern "C" void kernel_launch(void* const* d_in, const int* in_sizes, int n_in,
                              void* d_out, int out_size, void* d_ws, size_t ws_size,
                              hipStream_t stream) {
  const float* x     = (const float*)d_in[0];   // [8,32,4096] fp32
  const int*   wgt   = (const int*)d_in[1];     // [4096,16384] int32
  const float* scale = (const float*)d_in[2];   // [1,16384]
  const float* bias  = (const float*)d_in[3];   // [16384]
  float* out = (float*)d_out;
  unsigned short* xb = (unsigned short*)d_ws;   // 2 MiB fragment-major bf16 x

  cvt_x_frag<<<512, 256, 0, stream>>>(x, xb);
  gemm_qconv<<<512, 512, 0, stream>>>(xb, wgt, scale, bias, out);
}

// Round 3
// 367.616 us; speedup vs baseline: 1.0548x; 1.0548x over previous
//
#include <hip/hip_runtime.h>
#include <stdint.h>

// QuantConv1d: out[m][n] = (sum_k x[m][k]*w[k][n]) * scale[n] + bias[n]
// m=256, k=4096, n=16384. w arrives as int32 (harness-widened int8): 256 MiB stream.
// R1: xb stored A-fragment-major so A-loads are coalesced 1KiB wave reads.
// R2: single-barrier pipeline, LDS double-buffer, issue order A(it)->W(it+1)->
//     convert(W(it)) so vmcnt waits never drain the in-flight W queue. (365us)
// R3: BN=32/grid=512 experiment REGRESSED (+23us) -> 1-block/CU lockstep model
//     rejected; decomposition model confirmed across 3 rounds (timed region =
//     ~320us harness poison fills + cvt ~4us + gemm). Revert to BN=64/grid=256.
// R4: A-read dedup: 8 waves = 8 distinct m32-tiles x full n64 (2 accs/wave)
//     instead of 4(m)x2(n). Halves A L2 traffic (was 2x-duplicated across wn),
//     halves global A-load count; extra LDS B-reads are hidden under W stream.

typedef short bf16x8 __attribute__((ext_vector_type(8)));   // 8 bf16 = 16 B (MFMA A/B frag)
typedef float f32x16 __attribute__((ext_vector_type(16)));  // MFMA 32x32 accumulator
typedef int   i32x4  __attribute__((ext_vector_type(4)));
typedef int   i32x2  __attribute__((ext_vector_type(2)));
typedef unsigned short u16x4 __attribute__((ext_vector_type(4)));

#define K_DIM 4096
#define N_DIM 16384
#define BK 128
#define BN 64
#define NIT (K_DIM / BK)   // 32 K-iterations
#define KSTEPS 256         // K_DIM/16 total MFMA k-steps

__device__ __forceinline__ unsigned fbits(float f) {
  union { float f; unsigned u; } c; c.f = f; return c.u;
}
__device__ __forceinline__ unsigned short bf16rne(float f) {
  unsigned u = fbits(f);
  return (unsigned short)((u + 0x7FFFu + ((u >> 16) & 1u)) >> 16);
}

// ---------------- kernel 1: x fp32 -> bf16, A-fragment-major ----------------
// chunk c = (mt*256 + ks)*64 + lane holds A[m = mt*32 + (lane&31)]
//                                        [k = ks*16 + (lane>>5)*8 .. +8]  (16 B)
// => a wave's A-frag read for (mt, ks) is 64 contiguous 16 B chunks = 1 KiB.
__global__ __launch_bounds__(256) void cvt_x_frag(const float* __restrict__ x,
                                                  unsigned short* __restrict__ xb) {
  int c    = blockIdx.x * 256 + threadIdx.x;   // 131072 chunks
  int lane = c & 63;
  int ks   = (c >> 6) & 255;
  int mt   = c >> 14;
  int row  = mt * 32 + (lane & 31);
  int k0   = ks * 16 + (lane >> 5) * 8;
  const float4* p = (const float4*)(x + row * K_DIM + k0);
  float4 v0 = p[0], v1 = p[1];
  u16x4 o0, o1;
  o0.x = bf16rne(v0.x); o0.y = bf16rne(v0.y); o0.z = bf16rne(v0.z); o0.w = bf16rne(v0.w);
  o1.x = bf16rne(v1.x); o1.y = bf16rne(v1.y); o1.z = bf16rne(v1.z); o1.w = bf16rne(v1.w);
  u16x4* dst = (u16x4*)(xb + (size_t)c * 8);
  dst[0] = o0;
  dst[1] = o1;
}

// ---------------- kernel 2: GEMM ----------------
// block: 512 thr = 8 waves; wave w owns m32-tile mt=w x the block's full n64
// (two 32x32 accs, one per n32-half). grid: 256 blocks; block bx owns output
// columns [bx*64, bx*64+64) for ALL 256 rows => every W element fetched once.
__global__ __launch_bounds__(512, 2) void gemm_qconv(
    const unsigned short* __restrict__ xb,   // A-fragment-major bf16 (see cvt)
    const int* __restrict__ w,               // [4096][16384] int32
    const float* __restrict__ scale,
    const float* __restrict__ bias,
    float* __restrict__ out) {
  // B fragment store: frag fb = (c*8 + s), c = n32-tile (0..1), s = kstep (0..7).
  // slot sigma = khalf*32 + (n&31); reader lane reads slot==lane => contiguous b128.
  __shared__ i32x4 Blds[2][16 * 64];         // 2 x 16 KiB double buffer

  const int tid  = threadIdx.x;
  const int lane = tid & 63;
  const int wave = tid >> 6;                 // 0..7 : m32-tile
  const int l31  = lane & 31;
  const int half = lane >> 5;
  const int n0   = blockIdx.x * BN;

  // ---- W staging assignment: thread t covers 8 k-rows x 2 n-columns per iter ----
  const int n2 = tid & 31;                   // column pair (2*n2, 2*n2+1)
  const int k8 = tid >> 5;                   // 0..15 : k-rows [k8*8, k8*8+8)
  const int sW = k8 >> 1;                    // kstep this thread feeds
  const int hW = k8 & 1;                     // k-half within kstep
  const int nnA = n2 * 2, nnB = n2 * 2 + 1;
  const int slotA = ((nnA >> 5) * 8 + sW) * 64 + (hW * 32 + (nnA & 31));
  const int slotB = ((nnB >> 5) * 8 + sW) * 64 + (hW * 32 + (nnB & 31));

  const int* wbase = w + (k8 * 8) * N_DIM + n0 + n2 * 2;

  // prologue: prefetch W regs for iter 0 (16 ints = 8 x dwordx2, rows 256B-coalesced)
  i32x2 La[8], Lb[8];
#pragma unroll
  for (int i = 0; i < 8; ++i) La[i] = *(const i32x2*)(wbase + i * N_DIM);

  f32x16 acc0 = {};   // n32-half 0
  f32x16 acc1 = {};   // n32-half 1

  // A-fragment base: wave owns m-tile mt = wave (no duplication across waves)
  const bf16x8* afrag = (const bf16x8*)(xb + (size_t)(wave * KSTEPS) * 64 * 8);

  // Per-iteration body. Vmcnt queue at MFMA time: [A(IT) x8, W(IT+1) x8]
  //  - convert waits W(IT)  -> vmcnt(16): A + next W stay in flight
  //  - MFMA waits A(IT)     -> vmcnt(8):  next W stays in flight
  // Raw s_barrier (no vmcnt drain); lgkmcnt(0) makes ds_writes visible.
  // Double buffer => read(buf)@IT vs next write(buf)@IT+2 separated by the
  // IT+1 barrier + its lgkmcnt(0) => race-free with ONE barrier/iter.
#define ITER_BODY(IT, LCUR, LNEXT, BUFIDX)                                     \
  {                                                                            \
    bf16x8 A[8];                                                               \
    _Pragma("unroll")                                                          \
    for (int s = 0; s < 8; ++s) {                                              \
      A[s] = afrag[((IT) * 8 + s) * 64 + lane];                                \
    }                                                                          \
    __builtin_amdgcn_sched_barrier(0); /* pin: A issues before next W */       \
    {                                                                          \
      const int itn = ((IT) + 1 < NIT) ? (IT) + 1 : NIT - 1; /* dead@31=DCE */ \
      const int* wp = wbase + (size_t)itn * (BK * N_DIM);                      \
      _Pragma("unroll")                                                        \
      for (int i = 0; i < 8; ++i) LNEXT[i] = *(const i32x2*)(wp + i * N_DIM);  \
    }                                                                          \
    __builtin_amdgcn_sched_barrier(0); /* pin: W issues before convert wait */ \
    i32x4 chA, chB;                                                            \
    _Pragma("unroll")                                                          \
    for (int d = 0; d < 4; ++d) {                                              \
      float a0 = (float)LCUR[2 * d].x, a1 = (float)LCUR[2 * d + 1].x;          \
      float b0 = (float)LCUR[2 * d].y, b1 = (float)LCUR[2 * d + 1].y;          \
      chA[d] = (int)__builtin_amdgcn_perm(fbits(a1), fbits(a0), 0x07060302u);  \
      chB[d] = (int)__builtin_amdgcn_perm(fbits(b1), fbits(b0), 0x07060302u);  \
    }                                                                          \
    Blds[BUFIDX][slotA] = chA;                                                 \
    Blds[BUFIDX][slotB] = chB;                                                 \
    asm volatile("s_waitcnt lgkmcnt(0)" ::: "memory");                         \
    __builtin_amdgcn_s_barrier();                                              \
    __builtin_amdgcn_sched_barrier(0); /* no LDS reads above the barrier */    \
    _Pragma("unroll")                                                          \
    for (int s = 0; s < 8; ++s) {                                              \
      bf16x8 b0 = *(const bf16x8*)&Blds[BUFIDX][(0 * 8 + s) * 64 + lane];      \
      bf16x8 b1 = *(const bf16x8*)&Blds[BUFIDX][(1 * 8 + s) * 64 + lane];      \
      acc0 = __builtin_amdgcn_mfma_f32_32x32x16_bf16(A[s], b0, acc0, 0, 0, 0); \
      acc1 = __builtin_amdgcn_mfma_f32_32x32x16_bf16(A[s], b1, acc1, 0, 0, 0); \
    }                                                                          \
  }

#pragma unroll 1
  for (int it = 0; it < NIT; it += 2) {
    ITER_BODY(it,     La, Lb, 0)
    ITER_BODY(it + 1, Lb, La, 1)
  }
#undef ITER_BODY

  // epilogue: C/D map col=lane&31, row=(reg&3)+8*(reg>>2)+4*half
#pragma unroll
  for (int c = 0; c < 2; ++c) {
    const f32x16 acc = c ? acc1 : acc0;
    const int n = n0 + c * 32 + l31;
    const float sc = scale[n];
    const float bs = bias[n];
#pragma unroll
    for (int g = 0; g < 16; ++g) {
      const int m = wave * 32 + (g & 3) + 8 * (g >> 2) + 4 * half;
      out[m * N_DIM + n] = acc[g] * sc + bs;
    }
  }
}

extern "C" void kernel_launch(void* const* d_in, const int* in_sizes, int n_in,
                              void* d_out, int out_size, void* d_ws, size_t ws_size,
                              hipStream_t stream) {
  const float* x     = (const float*)d_in[0];   // [8,32,4096] fp32
  const int*   wgt   = (const int*)d_in[1];     // [4096,16384] int32
  const float* scale = (const float*)d_in[2];   // [1,16384]
  const float* bias  = (const float*)d_in[3];   // [16384]
  float* out = (float*)d_out;
  unsigned short* xb = (unsigned short*)d_ws;   // 2 MiB fragment-major bf16 x

  cvt_x_frag<<<512, 256, 0, stream>>>(x, xb);
  gemm_qconv<<<256, 512, 0, stream>>>(xb, wgt, scale, bias, out);
}